// Round 7
// baseline (302.952 us; speedup 1.0000x reference)
//
#include <hip/hip_runtime.h>
#include <hip/hip_bf16.h>

constexpr int kNodes = 100000;
constexpr int kEdges = 1600000;
constexpr int kCh    = 128;
constexpr int kCap   = 32;               // bucket row = 32 ints = one 128B line
constexpr int kOvfCap = 4096;            // overflow pairs (deg>32 nodes ~12 expected)
constexpr int kBinShift = 11;
constexpr int kBinSize  = 1 << kBinShift;                       // 2048 nodes/bin
constexpr int kBins  = (kNodes + kBinSize - 1) >> kBinShift;    // 49
constexpr int kBinBlocks = 128;          // phase-A blocks (512 thr): 12500 edges each
constexpr int kChunkCap = 384;           // per (block,bin) chunk; mean 255, +8 sigma
constexpr int kGemmBlocks = (kNodes + 127) / 128;               // 782
constexpr int kNodesPerB = 512;          // phase-B nodes per block (64KB LDS bucket)
constexpr int kFillBlocks = (kNodes + kNodesPerB - 1) / kNodesPerB;  // 196

typedef __attribute__((ext_vector_type(8))) short short8;
typedef __attribute__((ext_vector_type(4))) float floatx4;
typedef __attribute__((ext_vector_type(4))) int   intx4;

// =============== K1: phase-A binning (blocks [0,128)) + MFMA GEMM (rest) ===============
// Binning: NO global atomics. Block-private LDS counters index block-private per-bin chunks;
// chunk tail lines fill sequentially (32 x 4B entries per 128B line) -> L2 write-combining.
// Entry packs (d & 2047)<<17 | s  (kNodes < 2^17). GEMM: hs = bf16(x @ W), unscaled.

__global__ __launch_bounds__(512) void k_fused(const float* __restrict__ x,
                                               const float* __restrict__ W,
                                               const int* __restrict__ srcArr,
                                               const int* __restrict__ dstArr,
                                               unsigned* __restrict__ segs,
                                               int* __restrict__ segCnt,
                                               int* __restrict__ cntA,
                                               int* __restrict__ ovfCnt,
                                               int* __restrict__ ovfAFlag,
                                               int* __restrict__ ovfD,
                                               int* __restrict__ ovfS,
                                               __hip_bfloat16* __restrict__ hs) {
  __shared__ int lcnt[kBins];
  if (blockIdx.x < kBinBlocks) {
    for (int i = threadIdx.x; i < kBins; i += 512) lcnt[i] = 0;
    __syncthreads();
    const intx4* d4 = (const intx4*)dstArr;
    const intx4* s4 = (const intx4*)srcArr;
    unsigned* myseg = segs + (long)blockIdx.x * kBins * kChunkCap;
    for (int i = blockIdx.x * 512 + (int)threadIdx.x; i < kEdges / 4; i += kBinBlocks * 512) {
      intx4 dv = __builtin_nontemporal_load(d4 + i);
      intx4 sv = __builtin_nontemporal_load(s4 + i);
      #pragma unroll
      for (int k = 0; k < 4; k++) {
        int d = dv[k], s = sv[k];
        int bin = d >> kBinShift;
        int pos = atomicAdd(&lcnt[bin], 1);      // LDS atomic
        if (pos < kChunkCap) {
          myseg[bin * kChunkCap + pos] = ((unsigned)(d & (kBinSize - 1)) << 17) | (unsigned)s;
        } else {                                 // astronomically rare; exact fallback
          int o = atomicAdd(ovfCnt, 1);
          if (o < kOvfCap) { ovfD[o] = d; ovfS[o] = s; }
          atomicAdd(&cntA[d], 1);
          atomicAdd(ovfAFlag, 1);
        }
      }
    }
    __syncthreads();
    for (int i = threadIdx.x; i < kBins; i += 512) {
      int c = lcnt[i];
      segCnt[blockIdx.x * kBins + i] = c < kChunkCap ? c : kChunkCap;
    }
    return;
  }

  // ---- GEMM: 8 waves, wave handles 16 rows; 8 N-tiles of 16; K=128 in 4 chunks ----
  __shared__ short8 Bf[2048];  // 32 KB, B-fragment order
  for (int e = threadIdx.x; e < 2048; e += 512) {
    int lane = e & 63, c = (e >> 6) & 3, tt = e >> 8;
    int quad = lane >> 4, mcol = lane & 15;
    short8 v;
    #pragma unroll
    for (int j = 0; j < 8; j++) {
      __hip_bfloat16 h = __float2bfloat16(W[(c * 32 + quad * 8 + j) * kCh + tt * 16 + mcol]);
      v[j] = *(short*)&h;
    }
    Bf[e] = v;
  }
  __syncthreads();

  int wave = threadIdx.x >> 6;
  int lane = threadIdx.x & 63;
  int quad = lane >> 4;
  int mcol = lane & 15;
  int gb = blockIdx.x - kBinBlocks;
  long rowBase = ((long)gb * 8 + wave) * 16;
  if (rowBase >= kNodes) return;

  long arow = rowBase + mcol;
  if (arow >= kNodes) arow = kNodes - 1;  // clamp (stores guarded)
  const float* xp = x + arow * kCh;
  short8 afrag[4];
  #pragma unroll
  for (int c = 0; c < 4; c++) {
    const floatx4* p = (const floatx4*)(xp + c * 32 + quad * 8);
    floatx4 v0 = __builtin_nontemporal_load(p);
    floatx4 v1 = __builtin_nontemporal_load(p + 1);
    #pragma unroll
    for (int j = 0; j < 4; j++) {
      __hip_bfloat16 h0 = __float2bfloat16(v0[j]);
      __hip_bfloat16 h1 = __float2bfloat16(v1[j]);
      afrag[c][j]     = *(short*)&h0;
      afrag[c][j + 4] = *(short*)&h1;
    }
  }

  #pragma unroll
  for (int t = 0; t < 8; t++) {
    floatx4 acc = {0.f, 0.f, 0.f, 0.f};
    #pragma unroll
    for (int c = 0; c < 4; c++) {
      short8 b = Bf[(t * 4 + c) * 64 + lane];
      acc = __builtin_amdgcn_mfma_f32_16x16x32_bf16(afrag[c], b, acc, 0, 0, 0);
    }
    // C/D layout: col = lane&15, row = quad*4 + reg
    #pragma unroll
    for (int i = 0; i < 4; i++) {
      long r = rowBase + quad * 4 + i;
      if (r < kNodes) {
        __hip_bfloat16 h = __float2bfloat16(acc[i]);
        __builtin_nontemporal_store(*(short*)&h, (short*)hs + r * kCh + t * 16 + mcol);
      }
    }
  }
}

// =============== K2: phase-B LDS-staged bucket build + coalesced flush ===============
// One block per 512 dst nodes (within one bin). Scan the bin's 128 chunks, LDS-append,
// then flush full 128B bucket rows + cntC + dinv with coalesced nt stores.

__global__ __launch_bounds__(256) void k_fill(const unsigned* __restrict__ segs,
                                              const int* __restrict__ segCnt,
                                              const int* __restrict__ cntA,
                                              int* __restrict__ cntC,
                                              float* __restrict__ dinv,
                                              int* __restrict__ bucket,
                                              int* __restrict__ ovfCnt,
                                              int* __restrict__ ovfD,
                                              int* __restrict__ ovfS) {
  __shared__ int lsn[kBinBlocks];
  __shared__ int lcnt[kNodesPerB];
  __shared__ __align__(16) int lbkt[kNodesPerB][kCap];   // 64 KB

  int b   = blockIdx.x;
  int lo  = b * kNodesPerB;
  int bin = lo >> kBinShift;
  int binBase = bin << kBinShift;
  int sub = lo - binBase;                 // 0/512/1024/1536

  for (int i = threadIdx.x; i < kBinBlocks; i += 256) lsn[i] = segCnt[i * kBins + bin];
  for (int i = threadIdx.x; i < kNodesPerB; i += 256) lcnt[i] = 0;
  __syncthreads();

  for (int blk = 0; blk < kBinBlocks; blk++) {
    int n = lsn[blk];
    const unsigned* chunk = segs + ((long)blk * kBins + bin) * kChunkCap;
    for (int i = threadIdx.x; i < n; i += 256) {
      unsigned e = chunk[i];
      int r = (int)(e >> 17) - sub;
      if ((unsigned)r < (unsigned)kNodesPerB) {
        int pos = atomicAdd(&lcnt[r], 1);           // LDS atomic
        if (pos < kCap) {
          lbkt[r][pos] = (int)(e & 0x1ffff);
        } else {
          int o = atomicAdd(ovfCnt, 1);
          if (o < kOvfCap) { ovfD[o] = binBase + sub + r; ovfS[o] = (int)(e & 0x1ffff); }
        }
      }
    }
  }
  __syncthreads();

  int hi = lo + kNodesPerB; if (hi > kNodes) hi = kNodes;
  int nr = hi - lo;
  for (int idx = threadIdx.x; idx < nr * (kCap / 4); idx += 256) {
    int r = idx >> 3;                        // 8 int4 per row
    int q = idx & 7;
    intx4 v = *((const intx4*)&lbkt[r][0] + q);
    __builtin_nontemporal_store(v, (intx4*)(bucket + (long)(lo + r) * kCap) + q);
  }
  for (int r = threadIdx.x; r < nr; r += 256) {
    int c = lcnt[r];                         // raw bucket count (may exceed kCap)
    cntC[lo + r] = c;
    int t = c + cntA[lo + r];                // true degree incl. phase-A overflow
    dinv[lo + r] = rsqrtf((float)(t + 1));
  }
}

// =============== K3: aggregation, one wave per dst node ===============
// out[d] = dinv[d] * ( dinv[d]*h[d] + sum_s dinv[s]*h[s] + overflow ) + bias

__global__ __launch_bounds__(256) void k_aggregate(const int* __restrict__ cntC,
                                                   const int* __restrict__ bucket,
                                                   const float* __restrict__ dinv,
                                                   const int* __restrict__ ovfCnt,
                                                   const int* __restrict__ ovfAFlag,
                                                   const int* __restrict__ ovfD,
                                                   const int* __restrict__ ovfS,
                                                   const __hip_bfloat16* __restrict__ hs,
                                                   const float* __restrict__ bias,
                                                   float* __restrict__ out) {
  int gid  = blockIdx.x * 256 + threadIdx.x;
  int node = gid >> 6;
  int lane = gid & 63;
  if (node >= kNodes) return;

  const __hip_bfloat162* hbase = (const __hip_bfloat162*)hs;

  int degRaw = cntC[node];
  float dd = dinv[node];

  float2 sf = __bfloat1622float2(hbase[(long)node * (kCh / 2) + lane]);
  float acc0 = dd * sf.x;
  float acc1 = dd * sf.y;

  int c = degRaw < kCap ? degRaw : kCap;
  const int* bkt = bucket + (long)node * kCap;

  int j = 0;
  for (; j + 7 < c; j += 8) {
    int s[8];
    #pragma unroll
    for (int u = 0; u < 8; u++) s[u] = bkt[j + u];
    float dv[8];
    #pragma unroll
    for (int u = 0; u < 8; u++) dv[u] = dinv[s[u]];
    __hip_bfloat162 v[8];
    #pragma unroll
    for (int u = 0; u < 8; u++) v[u] = hbase[(long)s[u] * (kCh / 2) + lane];
    #pragma unroll
    for (int u = 0; u < 8; u++) {
      float2 f = __bfloat1622float2(v[u]);
      acc0 = fmaf(dv[u], f.x, acc0);
      acc1 = fmaf(dv[u], f.y, acc1);
    }
  }
  for (; j < c; ++j) {
    int s = bkt[j];
    float dv = dinv[s];
    float2 f = __bfloat1622float2(hbase[(long)s * (kCh / 2) + lane]);
    acc0 = fmaf(dv, f.x, acc0);
    acc1 = fmaf(dv, f.y, acc1);
  }

  if (degRaw > kCap || *ovfAFlag != 0) {   // exact overflow handling (tiny list)
    int n = *ovfCnt;
    if (n > kOvfCap) n = kOvfCap;
    for (int i = 0; i < n; i++) {
      if (ovfD[i] == node) {
        int s = ovfS[i];
        float2 f = __bfloat1622float2(hbase[(long)s * (kCh / 2) + lane]);
        acc0 = fmaf(dinv[s], f.x, acc0);
        acc1 = fmaf(dinv[s], f.y, acc1);
      }
    }
  }

  float2 b = ((const float2*)bias)[lane];
  float2 o;
  o.x = dd * acc0 + b.x;
  o.y = dd * acc1 + b.y;
  ((float2*)(out + (long)node * kCh))[lane] = o;
}

// =============== launch ===============

extern "C" void kernel_launch(void* const* d_in, const int* in_sizes, int n_in,
                              void* d_out, int out_size, void* d_ws, size_t ws_size,
                              hipStream_t stream) {
  const float* x    = (const float*)d_in[0];
  const int*   ei   = (const int*)d_in[1];      // [2, E] row-major int32
  const float* W    = (const float*)d_in[2];
  const float* bias = (const float*)d_in[3];
  float* out = (float*)d_out;

  const int* srcArr = ei;
  const int* dstArr = ei + kEdges;

  // workspace layout (bytes); total ~49.3 MB
  char* ws = (char*)d_ws;
  size_t off = 0;
  __hip_bfloat16* hs = (__hip_bfloat16*)(ws + off); off += (size_t)kNodes * kCh * 2;        // 25.6 MB
  int*   bucket  = (int*)     (ws + off); off += (size_t)kNodes * kCap * 4;                 // 12.8 MB
  unsigned* segs = (unsigned*)(ws + off); off += (size_t)kBinBlocks * kBins * kChunkCap * 4; // 9.6 MB
  float* dinv    = (float*)   (ws + off); off += (size_t)kNodes * 4;                        // 0.4 MB
  int*   cntC    = (int*)     (ws + off); off += (size_t)kNodes * 4;                        // 0.4 MB
  // ---- zeroed region (one memset) ----
  char* zbase = ws + off;
  int*   cntA    = (int*)(ws + off); off += (size_t)kNodes * 4;                             // 0.4 MB
  int*   segCnt  = (int*)(ws + off); off += (size_t)kBinBlocks * kBins * 4;                 // 25 KB
  int*   ovfCnt  = (int*)(ws + off); off += 64;
  int*   ovfAFlag= (int*)(ws + off); off += 64;
  size_t zbytes = (size_t)((ws + off) - zbase);
  int*   ovfD    = (int*)(ws + off); off += (size_t)kOvfCap * 4;
  int*   ovfS    = (int*)(ws + off); off += (size_t)kOvfCap * 4;

  (void)hipMemsetAsync(zbase, 0, zbytes, stream);

  k_fused<<<kBinBlocks + kGemmBlocks, 512, 0, stream>>>(x, W, srcArr, dstArr,
                                                        segs, segCnt, cntA,
                                                        ovfCnt, ovfAFlag, ovfD, ovfS, hs);

  k_fill<<<kFillBlocks, 256, 0, stream>>>(segs, segCnt, cntA, cntC, dinv, bucket,
                                          ovfCnt, ovfD, ovfS);

  long aggThreads = (long)kNodes * 64;
  int gAgg = (int)((aggThreads + 255) / 256);
  k_aggregate<<<gAgg, 256, 0, stream>>>(cntC, bucket, dinv, ovfCnt, ovfAFlag, ovfD, ovfS,
                                        hs, bias, out);
}

// Round 8
// 240.823 us; speedup vs baseline: 1.2580x; 1.2580x over previous
//
#include <hip/hip_runtime.h>
#include <hip/hip_bf16.h>

constexpr int kNodes = 100000;
constexpr int kEdges = 1600000;
constexpr int kCh    = 128;
constexpr int kCap   = 32;               // bucket slots per node (LDS); deg>32 via LDS ovf list
constexpr int kOvfCap = 4096;            // global spill pairs (phase-A chunk overflow; ~0 expected)
constexpr int kLOvf  = 512;              // per-block LDS overflow entries (deg>kCap excess)
constexpr int kBinShift = 8;
constexpr int kBinSize  = 1 << kBinShift;                       // 256 nodes/bin
constexpr int kBins  = (kNodes + kBinSize - 1) >> kBinShift;    // 391
constexpr int kABlocks = 128;            // phase-A blocks (512 thr): 12500 edges each
constexpr int kChunkCap = 64;            // slots per (Ablock,bin) chunk; mean 32, P(>64)~1e-7
constexpr int kGemmBlocks = (kNodes + 127) / 128;               // 782
constexpr int kAggBlocks = (kNodes + 63) / 64;                  // 1563, 64 nodes each

typedef __attribute__((ext_vector_type(8))) short short8;
typedef __attribute__((ext_vector_type(4))) float floatx4;
typedef __attribute__((ext_vector_type(4))) int   intx4;

// =============== K1: phase-A binning (blocks [0,128)) + MFMA GEMM (rest) ===============
// Binning: no global atomics. Block-private LDS counters -> block-private per-bin chunks.
// Entry = (d & 255) << 17 | s  (s < 2^17). GEMM: hs = bf16(x @ W), unscaled.

__global__ __launch_bounds__(512) void k_fused(const float* __restrict__ x,
                                               const float* __restrict__ W,
                                               const int* __restrict__ srcArr,
                                               const int* __restrict__ dstArr,
                                               unsigned* __restrict__ segs,
                                               int* __restrict__ segCnt,
                                               int* __restrict__ ovfCnt,
                                               int* __restrict__ ovfD,
                                               int* __restrict__ ovfS,
                                               __hip_bfloat16* __restrict__ hs) {
  if (blockIdx.x < kABlocks) {
    __shared__ int lcnt[kBins];
    for (int i = threadIdx.x; i < kBins; i += 512) lcnt[i] = 0;
    __syncthreads();
    const intx4* d4 = (const intx4*)dstArr;
    const intx4* s4 = (const intx4*)srcArr;
    unsigned* myseg = segs + (long)blockIdx.x * kBins * kChunkCap;
    for (int i = blockIdx.x * 512 + (int)threadIdx.x; i < kEdges / 4; i += kABlocks * 512) {
      intx4 dv = __builtin_nontemporal_load(d4 + i);
      intx4 sv = __builtin_nontemporal_load(s4 + i);
      #pragma unroll
      for (int k = 0; k < 4; k++) {
        int d = dv[k], s = sv[k];
        int bin = d >> kBinShift;
        int pos = atomicAdd(&lcnt[bin], 1);      // LDS atomic
        if (pos < kChunkCap) {
          myseg[bin * kChunkCap + pos] = ((unsigned)(d & (kBinSize - 1)) << 17) | (unsigned)s;
        } else {                                 // ~1e-7 per chunk; exact global fallback
          int o = atomicAdd(ovfCnt, 1);
          if (o < kOvfCap) { ovfD[o] = d; ovfS[o] = s; }
        }
      }
    }
    __syncthreads();
    for (int i = threadIdx.x; i < kBins; i += 512) {
      int c = lcnt[i];
      segCnt[blockIdx.x * kBins + i] = c < kChunkCap ? c : kChunkCap;
    }
    return;
  }

  // ---- GEMM: 8 waves, wave handles 16 rows; 8 N-tiles of 16; K=128 in 4 chunks ----
  __shared__ short8 Bf[2048];  // 32 KB, B-fragment order
  for (int e = threadIdx.x; e < 2048; e += 512) {
    int lane = e & 63, c = (e >> 6) & 3, tt = e >> 8;
    int quad = lane >> 4, mcol = lane & 15;
    short8 v;
    #pragma unroll
    for (int j = 0; j < 8; j++) {
      __hip_bfloat16 h = __float2bfloat16(W[(c * 32 + quad * 8 + j) * kCh + tt * 16 + mcol]);
      v[j] = *(short*)&h;
    }
    Bf[e] = v;
  }
  __syncthreads();

  int wave = threadIdx.x >> 6;
  int lane = threadIdx.x & 63;
  int quad = lane >> 4;
  int mcol = lane & 15;
  int gb = blockIdx.x - kABlocks;
  long rowBase = ((long)gb * 8 + wave) * 16;
  if (rowBase >= kNodes) return;

  long arow = rowBase + mcol;
  if (arow >= kNodes) arow = kNodes - 1;  // clamp (stores guarded)
  const float* xp = x + arow * kCh;
  short8 afrag[4];
  #pragma unroll
  for (int c = 0; c < 4; c++) {
    const floatx4* p = (const floatx4*)(xp + c * 32 + quad * 8);
    floatx4 v0 = __builtin_nontemporal_load(p);
    floatx4 v1 = __builtin_nontemporal_load(p + 1);
    #pragma unroll
    for (int j = 0; j < 4; j++) {
      __hip_bfloat16 h0 = __float2bfloat16(v0[j]);
      __hip_bfloat16 h1 = __float2bfloat16(v1[j]);
      afrag[c][j]     = *(short*)&h0;
      afrag[c][j + 4] = *(short*)&h1;
    }
  }

  #pragma unroll
  for (int t = 0; t < 8; t++) {
    floatx4 acc = {0.f, 0.f, 0.f, 0.f};
    #pragma unroll
    for (int c = 0; c < 4; c++) {
      short8 b = Bf[(t * 4 + c) * 64 + lane];
      acc = __builtin_amdgcn_mfma_f32_16x16x32_bf16(afrag[c], b, acc, 0, 0, 0);
    }
    // C/D layout: col = lane&15, row = quad*4 + reg
    #pragma unroll
    for (int i = 0; i < 4; i++) {
      long r = rowBase + quad * 4 + i;
      if (r < kNodes) {
        __hip_bfloat16 h = __float2bfloat16(acc[i]);
        __builtin_nontemporal_store(*(short*)&h, (short*)hs + r * kCh + t * 16 + mcol);
      }
    }
  }
}

// =============== K2: per-bin degree histogram -> dinv table (400KB, L2-resident) ===============

__global__ __launch_bounds__(256) void k_dinv(const unsigned* __restrict__ segs,
                                              const int* __restrict__ segCnt,
                                              const int* __restrict__ ovfCnt,
                                              const int* __restrict__ ovfD,
                                              float* __restrict__ dinv) {
  __shared__ int lsn[kABlocks];
  __shared__ int hist[kBinSize];
  int bin = blockIdx.x;
  for (int i = threadIdx.x; i < kABlocks; i += 256) lsn[i] = segCnt[i * kBins + bin];
  for (int i = threadIdx.x; i < kBinSize; i += 256) hist[i] = 0;
  __syncthreads();

  for (int slot = threadIdx.x; slot < kABlocks * kChunkCap; slot += 256) {
    int blk = slot >> 6, pos = slot & (kChunkCap - 1);
    if (pos < lsn[blk]) {
      unsigned e = segs[((long)blk * kBins + bin) * kChunkCap + pos];
      atomicAdd(&hist[e >> 17], 1);
    }
  }
  int n = *ovfCnt; if (n > kOvfCap) n = kOvfCap;
  for (int i = threadIdx.x; i < n; i += 256) {
    int d = ovfD[i];
    if ((d >> kBinShift) == bin) atomicAdd(&hist[d & (kBinSize - 1)], 1);
  }
  __syncthreads();
  int base = bin << kBinShift;
  for (int i = threadIdx.x; i < kBinSize; i += 256) {
    int node = base + i;
    if (node < kNodes) dinv[node] = rsqrtf((float)(hist[i] + 1));
  }
}

// =============== K3: fused bucket-build (LDS) + aggregation ===============
// One block per 64 dst nodes. Scan the bin's 128 chunks, LDS-append bucket lists,
// then aggregate directly from LDS: out[d] = dd*(dd*h[d] + sum dinv[s]*h[s]) + bias.

__global__ __launch_bounds__(512) void k_agg(const unsigned* __restrict__ segs,
                                             const int* __restrict__ segCnt,
                                             const int* __restrict__ ovfCnt,
                                             const int* __restrict__ ovfD,
                                             const int* __restrict__ ovfS,
                                             const float* __restrict__ dinv,
                                             const __hip_bfloat16* __restrict__ hs,
                                             const float* __restrict__ bias,
                                             float* __restrict__ out) {
  __shared__ int lsn[kABlocks];
  __shared__ int lcnt[64];
  __shared__ __align__(16) int lbkt[64][kCap];   // 8 KB
  __shared__ unsigned lovf[kLOvf];
  __shared__ int lovfn;

  int base = blockIdx.x * 64;
  int bin  = base >> kBinShift;
  int q    = (base >> 6) & 3;                    // quarter of the bin

  for (int i = threadIdx.x; i < kABlocks; i += 512) lsn[i] = segCnt[i * kBins + bin];
  for (int i = threadIdx.x; i < 64; i += 512) lcnt[i] = 0;
  if (threadIdx.x == 0) lovfn = 0;
  __syncthreads();

  for (int slot = threadIdx.x; slot < kABlocks * kChunkCap; slot += 512) {
    int blk = slot >> 6, pos = slot & (kChunkCap - 1);
    if (pos < lsn[blk]) {
      unsigned e = segs[((long)blk * kBins + bin) * kChunkCap + pos];
      int r = (int)(e >> 17) - q * 64;
      if ((unsigned)r < 64u) {
        int p = atomicAdd(&lcnt[r], 1);
        if (p < kCap) lbkt[r][p] = (int)(e & 0x1ffff);
        else { int o = atomicAdd(&lovfn, 1); if (o < kLOvf) lovf[o] = ((unsigned)r << 17) | (e & 0x1ffff); }
      }
    }
  }
  {  // global spill (phase-A chunk overflow, ~0 entries)
    int n = *ovfCnt; if (n > kOvfCap) n = kOvfCap;
    for (int i = threadIdx.x; i < n; i += 512) {
      int d = ovfD[i];
      if ((d >> 6) == blockIdx.x) {
        int r = d & 63;
        int p = atomicAdd(&lcnt[r], 1);
        if (p < kCap) lbkt[r][p] = ovfS[i];
        else { int o = atomicAdd(&lovfn, 1); if (o < kLOvf) lovf[o] = ((unsigned)r << 17) | (unsigned)ovfS[i]; }
      }
    }
  }
  __syncthreads();

  int wave = threadIdx.x >> 6;
  int lane = threadIdx.x & 63;
  const __hip_bfloat162* hbase = (const __hip_bfloat162*)hs;
  int novf = lovfn; if (novf > kLOvf) novf = kLOvf;

  for (int t = 0; t < 8; t++) {
    int r = wave * 8 + t;
    int node = base + r;
    if (node >= kNodes) break;

    float dd = dinv[node];
    float2 sf = __bfloat1622float2(hbase[(long)node * (kCh / 2) + lane]);
    float acc0 = dd * sf.x;
    float acc1 = dd * sf.y;

    int c = lcnt[r]; if (c > kCap) c = kCap;
    int j = 0;
    for (; j + 7 < c; j += 8) {
      int s[8];
      #pragma unroll
      for (int u = 0; u < 8; u++) s[u] = lbkt[r][j + u];
      float dv[8];
      #pragma unroll
      for (int u = 0; u < 8; u++) dv[u] = dinv[s[u]];
      __hip_bfloat162 v[8];
      #pragma unroll
      for (int u = 0; u < 8; u++) v[u] = hbase[(long)s[u] * (kCh / 2) + lane];
      #pragma unroll
      for (int u = 0; u < 8; u++) {
        float2 f = __bfloat1622float2(v[u]);
        acc0 = fmaf(dv[u], f.x, acc0);
        acc1 = fmaf(dv[u], f.y, acc1);
      }
    }
    for (; j < c; ++j) {
      int s = lbkt[r][j];
      float dv = dinv[s];
      float2 f = __bfloat1622float2(hbase[(long)s * (kCh / 2) + lane]);
      acc0 = fmaf(dv, f.x, acc0);
      acc1 = fmaf(dv, f.y, acc1);
    }
    for (int i = 0; i < novf; i++) {           // usually 0
      if ((int)(lovf[i] >> 17) == r) {
        int s = (int)(lovf[i] & 0x1ffff);
        float2 f = __bfloat1622float2(hbase[(long)s * (kCh / 2) + lane]);
        acc0 = fmaf(dinv[s], f.x, acc0);
        acc1 = fmaf(dinv[s], f.y, acc1);
      }
    }

    float2 b = ((const float2*)bias)[lane];
    float2 o;
    o.x = dd * acc0 + b.x;
    o.y = dd * acc1 + b.y;
    ((float2*)(out + (long)node * kCh))[lane] = o;
  }
}

// =============== launch ===============

extern "C" void kernel_launch(void* const* d_in, const int* in_sizes, int n_in,
                              void* d_out, int out_size, void* d_ws, size_t ws_size,
                              hipStream_t stream) {
  const float* x    = (const float*)d_in[0];
  const int*   ei   = (const int*)d_in[1];      // [2, E] row-major int32
  const float* W    = (const float*)d_in[2];
  const float* bias = (const float*)d_in[3];
  float* out = (float*)d_out;

  const int* srcArr = ei;
  const int* dstArr = ei + kEdges;

  // workspace layout (bytes); total ~39.5 MB
  char* ws = (char*)d_ws;
  size_t off = 0;
  __hip_bfloat16* hs = (__hip_bfloat16*)(ws + off); off += (size_t)kNodes * kCh * 2;         // 25.6 MB
  unsigned* segs = (unsigned*)(ws + off); off += (size_t)kABlocks * kBins * kChunkCap * 4;   // 12.8 MB
  float* dinv    = (float*)   (ws + off); off += (size_t)kNodes * 4;                         // 0.4 MB
  int*   segCnt  = (int*)     (ws + off); off += (size_t)kABlocks * kBins * 4;               // 200 KB
  int*   ovfCnt  = (int*)     (ws + off); off += 64;                                         // zeroed
  int*   ovfD    = (int*)     (ws + off); off += (size_t)kOvfCap * 4;
  int*   ovfS    = (int*)     (ws + off); off += (size_t)kOvfCap * 4;

  (void)hipMemsetAsync(ovfCnt, 0, 64, stream);

  k_fused<<<kABlocks + kGemmBlocks, 512, 0, stream>>>(x, W, srcArr, dstArr,
                                                      segs, segCnt, ovfCnt, ovfD, ovfS, hs);

  k_dinv<<<kBins, 256, 0, stream>>>(segs, segCnt, ovfCnt, ovfD, dinv);

  k_agg<<<kAggBlocks, 512, 0, stream>>>(segs, segCnt, ovfCnt, ovfD, ovfS,
                                        dinv, hs, bias, out);
}

// Round 9
// 233.767 us; speedup vs baseline: 1.2960x; 1.0302x over previous
//
#include <hip/hip_runtime.h>
#include <hip/hip_bf16.h>

constexpr int kNodes = 100000;
constexpr int kEdges = 1600000;
constexpr int kCh    = 128;
constexpr int kCap   = 32;               // LDS bucket slots per node; excess via LDS ovf list
constexpr int kLOvf  = 256;              // per-block LDS overflow entries (deg>kCap excess)
constexpr int kBinShift = 7;
constexpr int kBinSize  = 1 << kBinShift;                       // 128 nodes/bin
constexpr int kBins  = (kNodes + kBinSize - 1) >> kBinShift;    // 782
constexpr int kABlocks = 128;            // phase-A blocks (512 thr): 12500 edges each
constexpr int kChunkCap = 32;            // slots per (Ablock,bin) chunk = one 128B line; mean 16
constexpr int kSpillCap = 64;            // per-Ablock spill pairs (~15 total expected)
constexpr int kGemmBlocks = (kNodes + 127) / 128;               // 782

typedef __attribute__((ext_vector_type(8))) short short8;
typedef __attribute__((ext_vector_type(4))) float floatx4;
typedef __attribute__((ext_vector_type(4))) int   intx4;
typedef __attribute__((ext_vector_type(2))) float floatx2;

// =============== K1: phase-A binning (blocks [0,128)) + MFMA GEMM (rest) ===============
// Binning: no global atomics, no zero-init needed. Block-private LDS counters -> block-private
// per-bin chunks (one 128B line each). Chunk overflow -> per-block spill arrays (LDS-counted,
// counts written unconditionally). Entry = (d & 127) << 17 | s  (s < 2^17).
// GEMM: hs = bf16(x @ W), unscaled (dinv applied at aggregation).

__global__ __launch_bounds__(512) void k_fused(const float* __restrict__ x,
                                               const float* __restrict__ W,
                                               const int* __restrict__ srcArr,
                                               const int* __restrict__ dstArr,
                                               unsigned* __restrict__ segs,
                                               int* __restrict__ segCnt,
                                               int* __restrict__ spillCnt,
                                               int* __restrict__ spillD,
                                               int* __restrict__ spillS,
                                               __hip_bfloat16* __restrict__ hs) {
  if (blockIdx.x < kABlocks) {
    __shared__ int lcnt[kBins];
    __shared__ int lspilln;
    for (int i = threadIdx.x; i < kBins; i += 512) lcnt[i] = 0;
    if (threadIdx.x == 0) lspilln = 0;
    __syncthreads();
    const intx4* d4 = (const intx4*)dstArr;
    const intx4* s4 = (const intx4*)srcArr;
    unsigned* myseg = segs + (long)blockIdx.x * kBins * kChunkCap;
    for (int i = blockIdx.x * 512 + (int)threadIdx.x; i < kEdges / 4; i += kABlocks * 512) {
      intx4 dv = __builtin_nontemporal_load(d4 + i);
      intx4 sv = __builtin_nontemporal_load(s4 + i);
      #pragma unroll
      for (int k = 0; k < 4; k++) {
        int d = dv[k], s = sv[k];
        int bin = d >> kBinShift;
        int pos = atomicAdd(&lcnt[bin], 1);      // LDS atomic
        if (pos < kChunkCap) {
          myseg[(bin << 5) + pos] = ((unsigned)(d & (kBinSize - 1)) << 17) | (unsigned)s;
        } else {                                 // rare exact fallback (~15 total expected)
          int o = atomicAdd(&lspilln, 1);
          if (o < kSpillCap) {
            spillD[blockIdx.x * kSpillCap + o] = d;
            spillS[blockIdx.x * kSpillCap + o] = s;
          }
        }
      }
    }
    __syncthreads();
    for (int i = threadIdx.x; i < kBins; i += 512) {
      int c = lcnt[i];
      segCnt[blockIdx.x * kBins + i] = c < kChunkCap ? c : kChunkCap;
    }
    if (threadIdx.x == 0) {
      int n = lspilln;
      spillCnt[blockIdx.x] = n < kSpillCap ? n : kSpillCap;
    }
    return;
  }

  // ---- GEMM: 8 waves, wave handles 16 rows; 8 N-tiles of 16; K=128 in 4 chunks ----
  __shared__ short8 Bf[2048];  // 32 KB, B-fragment order
  for (int e = threadIdx.x; e < 2048; e += 512) {
    int lane = e & 63, c = (e >> 6) & 3, tt = e >> 8;
    int quad = lane >> 4, mcol = lane & 15;
    short8 v;
    #pragma unroll
    for (int j = 0; j < 8; j++) {
      __hip_bfloat16 h = __float2bfloat16(W[(c * 32 + quad * 8 + j) * kCh + tt * 16 + mcol]);
      v[j] = *(short*)&h;
    }
    Bf[e] = v;
  }
  __syncthreads();

  int wave = threadIdx.x >> 6;
  int lane = threadIdx.x & 63;
  int quad = lane >> 4;
  int mcol = lane & 15;
  int gb = blockIdx.x - kABlocks;
  long rowBase = ((long)gb * 8 + wave) * 16;
  if (rowBase >= kNodes) return;

  long arow = rowBase + mcol;
  if (arow >= kNodes) arow = kNodes - 1;  // clamp (stores guarded)
  const float* xp = x + arow * kCh;
  short8 afrag[4];
  #pragma unroll
  for (int c = 0; c < 4; c++) {
    const floatx4* p = (const floatx4*)(xp + c * 32 + quad * 8);
    floatx4 v0 = __builtin_nontemporal_load(p);
    floatx4 v1 = __builtin_nontemporal_load(p + 1);
    #pragma unroll
    for (int j = 0; j < 4; j++) {
      __hip_bfloat16 h0 = __float2bfloat16(v0[j]);
      __hip_bfloat16 h1 = __float2bfloat16(v1[j]);
      afrag[c][j]     = *(short*)&h0;
      afrag[c][j + 4] = *(short*)&h1;
    }
  }

  #pragma unroll
  for (int t = 0; t < 8; t++) {
    floatx4 acc = {0.f, 0.f, 0.f, 0.f};
    #pragma unroll
    for (int c = 0; c < 4; c++) {
      short8 b = Bf[(t * 4 + c) * 64 + lane];
      acc = __builtin_amdgcn_mfma_f32_16x16x32_bf16(afrag[c], b, acc, 0, 0, 0);
    }
    // C/D layout: col = lane&15, row = quad*4 + reg
    #pragma unroll
    for (int i = 0; i < 4; i++) {
      long r = rowBase + quad * 4 + i;
      if (r < kNodes) {
        __hip_bfloat16 h = __float2bfloat16(acc[i]);
        __builtin_nontemporal_store(*(short*)&h, (short*)hs + r * kCh + t * 16 + mcol);
      }
    }
  }
}

// =============== K2: per-bin degree histogram -> dinv table (400KB, L2-resident) ===============

__global__ __launch_bounds__(256) void k_dinv(const unsigned* __restrict__ segs,
                                              const int* __restrict__ segCnt,
                                              const int* __restrict__ spillCnt,
                                              const int* __restrict__ spillD,
                                              float* __restrict__ dinv) {
  __shared__ int lsn[kABlocks];
  __shared__ int lsp[kABlocks];
  __shared__ int hist[kBinSize];
  int bin = blockIdx.x;
  for (int i = threadIdx.x; i < kABlocks; i += 256) {
    lsn[i] = segCnt[i * kBins + bin];
    lsp[i] = spillCnt[i];
  }
  for (int i = threadIdx.x; i < kBinSize; i += 256) hist[i] = 0;
  __syncthreads();

  for (int slot = threadIdx.x; slot < kABlocks * kChunkCap; slot += 256) {
    int blk = slot >> 5, pos = slot & 31;
    if (pos < lsn[blk]) {
      unsigned e = segs[((long)blk * kBins + bin) * kChunkCap + pos];
      atomicAdd(&hist[e >> 17], 1);
    }
  }
  for (int i = threadIdx.x; i < kABlocks * kSpillCap; i += 256) {
    int blk = i >> 6, o = i & 63;
    if (o < lsp[blk]) {
      int d = spillD[blk * kSpillCap + o];
      if ((d >> kBinShift) == bin) atomicAdd(&hist[d & (kBinSize - 1)], 1);
    }
  }
  __syncthreads();
  int base = bin << kBinShift;
  for (int i = threadIdx.x; i < kBinSize; i += 256) {
    int node = base + i;
    if (node < kNodes) dinv[node] = rsqrtf((float)(hist[i] + 1));
  }
}

// =============== K3: fused bucket-build (LDS) + aggregation, block == bin ===============
// One block per 128 dst nodes. Scan exactly this bin's chunks (zero filter waste),
// LDS-append bucket lists, then aggregate: out[d] = dd*(dd*h[d] + sum dinv[s]*h[s]) + bias.

__global__ __launch_bounds__(512) void k_agg(const unsigned* __restrict__ segs,
                                             const int* __restrict__ segCnt,
                                             const int* __restrict__ spillCnt,
                                             const int* __restrict__ spillD,
                                             const int* __restrict__ spillS,
                                             const float* __restrict__ dinv,
                                             const __hip_bfloat16* __restrict__ hs,
                                             const float* __restrict__ bias,
                                             float* __restrict__ out) {
  __shared__ int lsn[kABlocks];
  __shared__ int lsp[kABlocks];
  __shared__ int lcnt[kBinSize];
  __shared__ __align__(16) int lbkt[kBinSize][kCap];   // 16 KB
  __shared__ unsigned lovf[kLOvf];
  __shared__ int lovfn;

  int bin  = blockIdx.x;
  int base = bin << kBinShift;

  for (int i = threadIdx.x; i < kABlocks; i += 512) {
    lsn[i] = segCnt[i * kBins + bin];
    lsp[i] = spillCnt[i];
  }
  for (int i = threadIdx.x; i < kBinSize; i += 512) lcnt[i] = 0;
  if (threadIdx.x == 0) lovfn = 0;
  __syncthreads();

  for (int slot = threadIdx.x; slot < kABlocks * kChunkCap; slot += 512) {
    int blk = slot >> 5, pos = slot & 31;
    if (pos < lsn[blk]) {
      unsigned e = segs[((long)blk * kBins + bin) * kChunkCap + pos];
      int r = (int)(e >> 17);
      int p = atomicAdd(&lcnt[r], 1);
      if (p < kCap) lbkt[r][p] = (int)(e & 0x1ffff);
      else { int o = atomicAdd(&lovfn, 1); if (o < kLOvf) lovf[o] = ((unsigned)r << 17) | (e & 0x1ffff); }
    }
  }
  for (int i = threadIdx.x; i < kABlocks * kSpillCap; i += 512) {
    int blk = i >> 6, o = i & 63;
    if (o < lsp[blk]) {
      int d = spillD[blk * kSpillCap + o];
      if ((d >> kBinShift) == bin) {
        int r = d & (kBinSize - 1);
        int s = spillS[blk * kSpillCap + o];
        int p = atomicAdd(&lcnt[r], 1);
        if (p < kCap) lbkt[r][p] = s;
        else { int o2 = atomicAdd(&lovfn, 1); if (o2 < kLOvf) lovf[o2] = ((unsigned)r << 17) | (unsigned)s; }
      }
    }
  }
  __syncthreads();

  int wave = threadIdx.x >> 6;
  int lane = threadIdx.x & 63;
  const __hip_bfloat162* hbase = (const __hip_bfloat162*)hs;
  int novf = lovfn; if (novf > kLOvf) novf = kLOvf;

  for (int t = 0; t < 16; t++) {
    int r = wave * 16 + t;
    int node = base + r;
    if (node >= kNodes) continue;

    float dd = dinv[node];
    float2 sf = __bfloat1622float2(hbase[(long)node * (kCh / 2) + lane]);
    float acc0 = dd * sf.x;
    float acc1 = dd * sf.y;

    int c = lcnt[r]; if (c > kCap) c = kCap;
    int j = 0;
    for (; j + 7 < c; j += 8) {
      int s[8];
      #pragma unroll
      for (int u = 0; u < 8; u++) s[u] = lbkt[r][j + u];
      float dv[8];
      #pragma unroll
      for (int u = 0; u < 8; u++) dv[u] = dinv[s[u]];
      __hip_bfloat162 v[8];
      #pragma unroll
      for (int u = 0; u < 8; u++) v[u] = hbase[(long)s[u] * (kCh / 2) + lane];
      #pragma unroll
      for (int u = 0; u < 8; u++) {
        float2 f = __bfloat1622float2(v[u]);
        acc0 = fmaf(dv[u], f.x, acc0);
        acc1 = fmaf(dv[u], f.y, acc1);
      }
    }
    for (; j < c; ++j) {
      int s = lbkt[r][j];
      float dv = dinv[s];
      float2 f = __bfloat1622float2(hbase[(long)s * (kCh / 2) + lane]);
      acc0 = fmaf(dv, f.x, acc0);
      acc1 = fmaf(dv, f.y, acc1);
    }
    for (int i = 0; i < novf; i++) {           // usually 0 entries
      if ((int)(lovf[i] >> 17) == r) {
        int s = (int)(lovf[i] & 0x1ffff);
        float2 f = __bfloat1622float2(hbase[(long)s * (kCh / 2) + lane]);
        acc0 = fmaf(dinv[s], f.x, acc0);
        acc1 = fmaf(dinv[s], f.y, acc1);
      }
    }

    float2 b = ((const float2*)bias)[lane];
    floatx2 o;
    o[0] = dd * acc0 + b.x;
    o[1] = dd * acc1 + b.y;
    __builtin_nontemporal_store(o, (floatx2*)(out + (long)node * kCh) + lane);
  }
}

// =============== launch ===============

extern "C" void kernel_launch(void* const* d_in, const int* in_sizes, int n_in,
                              void* d_out, int out_size, void* d_ws, size_t ws_size,
                              hipStream_t stream) {
  const float* x    = (const float*)d_in[0];
  const int*   ei   = (const int*)d_in[1];      // [2, E] row-major int32
  const float* W    = (const float*)d_in[2];
  const float* bias = (const float*)d_in[3];
  float* out = (float*)d_out;

  const int* srcArr = ei;
  const int* dstArr = ei + kEdges;

  // workspace layout (bytes); total ~39.7 MB; NO zero-init required anywhere
  char* ws = (char*)d_ws;
  size_t off = 0;
  __hip_bfloat16* hs = (__hip_bfloat16*)(ws + off); off += (size_t)kNodes * kCh * 2;         // 25.6 MB
  unsigned* segs = (unsigned*)(ws + off); off += (size_t)kABlocks * kBins * kChunkCap * 4;   // 12.8 MB
  float* dinv    = (float*)   (ws + off); off += (size_t)kNodes * 4;                         // 0.4 MB
  int*   segCnt  = (int*)     (ws + off); off += (size_t)kABlocks * kBins * 4;               // 0.4 MB
  int*   spillCnt= (int*)     (ws + off); off += (size_t)kABlocks * 4;
  int*   spillD  = (int*)     (ws + off); off += (size_t)kABlocks * kSpillCap * 4;
  int*   spillS  = (int*)     (ws + off); off += (size_t)kABlocks * kSpillCap * 4;

  k_fused<<<kABlocks + kGemmBlocks, 512, 0, stream>>>(x, W, srcArr, dstArr,
                                                      segs, segCnt, spillCnt, spillD, spillS, hs);

  k_dinv<<<kBins, 256, 0, stream>>>(segs, segCnt, spillCnt, spillD, dinv);

  k_agg<<<kBins, 512, 0, stream>>>(segs, segCnt, spillCnt, spillD, spillS,
                                   dinv, hs, bias, out);
}